// Round 4
// baseline (5068.213 us; speedup 1.0000x reference)
//
#include <hip/hip_runtime.h>

typedef unsigned short u16;
typedef short short8 __attribute__((ext_vector_type(8)));
typedef float f32x4 __attribute__((ext_vector_type(4)));
typedef unsigned int u32x4 __attribute__((ext_vector_type(4)));
typedef unsigned int u32x2 __attribute__((ext_vector_type(2)));
typedef unsigned short u16x4 __attribute__((ext_vector_type(4)));

#define Bsz 32
#define Tsz 512
#define Dsz 1024
#define Usz 1024
#define Gsz 4096   // 4*U

// ---- bf16 helpers (manual RNE) ----
static __device__ __forceinline__ u16 f2bf(float f) {
    unsigned int u = __float_as_uint(f);
    unsigned int lsb = (u >> 16) & 1u;
    u += 0x7fffu + lsb;
    return (u16)(u >> 16);
}
static __device__ __forceinline__ float bf2f(u16 b) {
    return __uint_as_float(((unsigned int)b) << 16);
}

// =====================================================================
// Pack kernels: MFMA-fragment-ordered bf16 buffers.
// A-frag (16x16x32): lane L holds A[m = mt*16 + (L&15)][k = kb*32 + (L>>4)*8 + j]
// B-frag:            lane L holds B[k = kb*32 + (L>>4)*8 + j][n = nt*16 + (L&15)]
// Flat: buf[((tile*32 + kb)*64 + L)*8 + j] -> lane-contiguous 16B chunks.
// =====================================================================

__global__ __launch_bounds__(256) void pack_a(const float* __restrict__ x, u16* __restrict__ Af) {
    size_t tid = (size_t)blockIdx.x * 256 + threadIdx.x;
    int L = (int)(tid & 63);
    size_t mtkb = tid >> 6;
    int kb = (int)(mtkb & 31);
    int mt = (int)(mtkb >> 5);
    int m  = mt * 16 + (L & 15);
    int d0 = kb * 32 + (L >> 4) * 8;
    const float* src = x + (size_t)m * Dsz + d0;
    short8 v;
#pragma unroll
    for (int j = 0; j < 8; ++j) v[j] = (short)f2bf(src[j]);
    *(short8*)(Af + tid * 8) = v;
}

__global__ __launch_bounds__(256) void pack_b(const float* __restrict__ W, u16* __restrict__ Bf) {
    size_t tid = (size_t)blockIdx.x * 256 + threadIdx.x;
    int L = (int)(tid & 63);
    size_t ntkb = tid >> 6;
    int kb = (int)(ntkb & 31);
    int nt = (int)(ntkb >> 5);
    int n  = nt * 16 + (L & 15);
    int k0 = kb * 32 + (L >> 4) * 8;
    short8 v;
#pragma unroll
    for (int j = 0; j < 8; ++j) v[j] = (short)f2bf(W[(size_t)(k0 + j) * Gsz + n]);
    *(short8*)(Bf + tid * 8) = v;
}

// R -> Rp gate-interleaved: tile=blk (0..255), col c=gate*4+du -> g=gate*1024+blk*4+du.
// Also zeroes the 512 barrier flags (two groups; ws is poisoned 0xAA before every call!).
__global__ __launch_bounds__(256) void pack_r(const float* __restrict__ R, u16* __restrict__ Rp,
                                              unsigned* __restrict__ flags) {
    if (blockIdx.x < 2) flags[blockIdx.x * 256 + threadIdx.x] = 0;
    size_t tid = (size_t)blockIdx.x * 256 + threadIdx.x;
    int L = (int)(tid & 63);
    size_t bkkb = tid >> 6;
    int kb  = (int)(bkkb & 31);
    int blk = (int)(bkkb >> 5);
    int c = L & 15;
    int gate = c >> 2, du = c & 3;
    int g = gate * 1024 + blk * 4 + du;
    int k0 = kb * 32 + (L >> 4) * 8;
    short8 v;
#pragma unroll
    for (int j = 0; j < 8; ++j) v[j] = (short)f2bf(R[(size_t)(k0 + j) * Gsz + g]);
    *(short8*)(Rp + tid * 8) = v;
}

// =====================================================================
// GEMM1: x_proj = X @ W; 128x128 tile, 4 waves. Epilogue writes the
// scan-friendly layout: [t][b][blk(256)][du(4)][gate(4)] so each scan
// gate-lane reads exactly one float4/u16x4 per (t,b).
// =====================================================================
__global__ __launch_bounds__(256) void gemm1(const u16* __restrict__ Af, const u16* __restrict__ Bf,
                                             float* __restrict__ xpf, u16* __restrict__ xph, int xp32) {
    __shared__ u16 smem[16 * 512];
    int bm = blockIdx.x >> 5;
    int bn = blockIdx.x & 31;
    int tid = threadIdx.x;
    int w = tid >> 6, ln = tid & 63;
    int mw = w & 1, nw = w >> 1;

    f32x4 acc[4][4];
#pragma unroll
    for (int i = 0; i < 4; ++i)
#pragma unroll
        for (int j = 0; j < 4; ++j) acc[i][j] = (f32x4){0.f, 0.f, 0.f, 0.f};

    for (int kb = 0; kb < 32; ++kb) {
        short8 tmp[4];
#pragma unroll
        for (int c2 = 0; c2 < 4; ++c2) {
            int chunk = w * 4 + c2;
            const u16* src = (chunk < 8)
                ? Af + (((size_t)(bm * 8 + chunk) * 32 + kb) * 64 + ln) * 8
                : Bf + (((size_t)(bn * 8 + (chunk - 8)) * 32 + kb) * 64 + ln) * 8;
            tmp[c2] = *(const short8*)src;
        }
#pragma unroll
        for (int c2 = 0; c2 < 4; ++c2) {
            int chunk = w * 4 + c2;
            *(short8*)(smem + chunk * 512 + ln * 8) = tmp[c2];
        }
        __syncthreads();
        short8 av[4], bv[4];
#pragma unroll
        for (int i = 0; i < 4; ++i) av[i] = *(const short8*)(smem + (mw * 4 + i) * 512 + ln * 8);
#pragma unroll
        for (int j = 0; j < 4; ++j) bv[j] = *(const short8*)(smem + (8 + nw * 4 + j) * 512 + ln * 8);
#pragma unroll
        for (int i = 0; i < 4; ++i)
#pragma unroll
            for (int j = 0; j < 4; ++j)
                acc[i][j] = __builtin_amdgcn_mfma_f32_16x16x32_bf16(av[i], bv[j], acc[i][j], 0, 0, 0);
        __syncthreads();
    }

    int quad = ln >> 4, c15 = ln & 15;
#pragma unroll
    for (int i = 0; i < 4; ++i) {
        int mt_g = bm * 8 + mw * 4 + i;
#pragma unroll
        for (int j = 0; j < 4; ++j) {
            int g = (bn * 8 + nw * 4 + j) * 16 + c15;
            int p = ((g & 1023) >> 2) * 16 + (g & 3) * 4 + (g >> 10);
#pragma unroll
            for (int r = 0; r < 4; ++r) {
                int row = mt_g * 16 + quad * 4 + r;
                int bb = row >> 9, tt = row & 511;
                size_t o = ((size_t)tt * Bsz + bb) * Gsz + p;
                if (xp32) xpf[o] = acc[i][j][r];
                else      xph[o] = f2bf(acc[i][j][r]);
            }
        }
    }
}

// =====================================================================
// Scan: 256 blocks x 512 threads (8 waves), TWO batch-group chains.
//   waves 0-3 : MFMA (K-slice w*256, alternating G0/G1 phases)
//   wave  4/5 : gate wave for G0/G1 (reduce + gates + h/flag store)
//   wave  6/7 : SENTINEL for G0/G1 — spins on the 256 global flags and
//               posts LDS ready[G]=s when all reach s.  This takes the
//               LLC flag-poll round trips OFF the MFMA critical path.
// NO __syncthreads in the steady loop.  Intra-block sync is LDS flags:
//   MFMA  : wait ready[G] >= t+1 -> bypass-load h -> MFMA ->
//           partial[G][t&1][w] -> lgkmcnt(0) -> done[G][w] = t+1
//   gate G: wait done[G][*] >= t+1 -> reduce -> gates -> out ->
//           bypass-store h -> vmcnt(0) -> flag_G = t+2 -> xproj prefetch
// partial[] parity double-buffer is race-free: MFMA at t+2 requires
// flags >= t+3 everywhere incl. own block => own gate finished t+1 =>
// partial[t&1] consumed.  proj is private to each gate wave.
// =====================================================================
__global__ __launch_bounds__(512) void scan_all(const float* __restrict__ xpf,
                                                const u16* __restrict__ xph, int xp32,
                                                const u16* __restrict__ Rp,
                                                const float* __restrict__ bias,
                                                u16* __restrict__ hbf, float* __restrict__ out,
                                                unsigned* __restrict__ flags) {
    __shared__ f32x4 partial[2][2][4][64];   // [G][par][wave][lane] 16KB
    __shared__ float proj[2][16][17];        // per-gate-wave transpose buffer
    __shared__ int ready_sh[2];              // sentinel -> MFMA
    __shared__ int done_sh[2][4];            // MFMA -> gate

    int tid = threadIdx.x;
    int blk = blockIdx.x;
    int w = tid >> 6, ln = tid & 63, quad = ln >> 4, c15 = ln & 15;
    int bq = ln >> 2, du = ln & 3;           // gate-wave lane decomposition
    int u_g = blk * 4 + du;

    unsigned* flags0 = flags;                // group 0 flags[256]
    unsigned* flags1 = flags + 256;          // group 1 flags[256]

    u16* h00 = hbf;                          // G0 parity0 (written at even t)
    u16* h01 = hbf + 16384;                  // G0 parity1 (odd t; zeros for t=0)
    u16* h10 = hbf + 32768;                  // G1 parity0
    u16* h11 = hbf + 49152;                  // G1 parity1

    // ---- init LDS sync state ----
    if (tid == 0) { ready_sh[0] = 0; ready_sh[1] = 0; }
    if (tid < 8) ((int*)done_sh)[tid] = 0;

    // ---- zero h_{-1} (parity-1 buffers, both groups) via bypass stores ----
    if (tid < 256) {
        u32x4 z = (u32x4){0u, 0u, 0u, 0u};
#pragma unroll
        for (int i = 0; i < 8; ++i) {
            u16* p0 = h01 + tid * 64 + i * 8;
            u16* p1 = h11 + tid * 64 + i * 8;
            asm volatile("global_store_dwordx4 %0, %1, off sc0 sc1" :: "v"(p0), "v"(z) : "memory");
            asm volatile("global_store_dwordx4 %0, %1, off sc0 sc1" :: "v"(p1), "v"(z) : "memory");
        }
    }

    float bi0 = 0.f, bi1 = 0.f, bi2 = 0.f, bi3 = 0.f;
    f32x4 xr4 = (f32x4){0.f, 0.f, 0.f, 0.f};
    u32x2 xr2 = (u32x2){0u, 0u};

    if (w == 4 || w == 5) {                  // gate waves: bias + t=0 x_proj
        int G = w - 4;
        bi0 = bias[u_g]; bi1 = bias[1024 + u_g]; bi2 = bias[2048 + u_g]; bi3 = bias[3072 + u_g];
        size_t o0 = (size_t)(G * 16 + bq) * Gsz + blk * 16 + du * 4;   // t=0
        if (xp32) xr4 = *(const f32x4*)(xpf + o0);
        else      xr2 = *(const u32x2*)(xph + o0);
    }
    asm volatile("s_waitcnt vmcnt(0)" ::: "memory");
    __builtin_amdgcn_sched_barrier(0);
    __syncthreads();
    if (tid == 0) {
        unsigned one = 1;
        unsigned* f0 = flags0 + blk;
        unsigned* f1 = flags1 + blk;
        asm volatile("global_store_dword %0, %1, off sc0 sc1" :: "v"(f0), "v"(one) : "memory");
        asm volatile("global_store_dword %0, %1, off sc0 sc1" :: "v"(f1), "v"(one) : "memory");
    }

    if (w < 4) {
        // ================= MFMA role =================
        // loop-invariant R fragments: 8 x short8 = 32 VGPRs (safe to hoist)
        short8 rB[8];
#pragma unroll
        for (int kk = 0; kk < 8; ++kk)
            rB[kk] = *(const short8*)(Rp + (size_t)blk * 16384 + (size_t)(((w * 8 + kk) * 64 + ln) * 8));

        volatile int* rdy0 = &ready_sh[0];
        volatile int* rdy1 = &ready_sh[1];

        for (int t = 0; t < Tsz; ++t) {
#pragma unroll
            for (int G = 0; G < 2; ++G) {
                // ---- wait for sentinel's verdict (LDS, cheap) ----
                volatile int* rdy = G ? rdy1 : rdy0;
                while (*rdy < t + 1) { }
                __builtin_amdgcn_sched_barrier(0);

                // ---- bypass-load this wave's h_{t-1} fragment (8 x 16B/lane) ----
                const u16* hload = G ? ((t & 1) ? h10 : h11) : ((t & 1) ? h00 : h01);
                const u16* aBw = hload + (size_t)c15 * 1024 + w * 256 + quad * 8;
                short8 av[8];
#define LDH(i, OFF) asm volatile("global_load_dwordx4 %0, %1, off offset:" OFF " sc0 sc1" \
                                 : "=v"(av[i]) : "v"(aBw))
                LDH(0, "0");   LDH(1, "64");  LDH(2, "128"); LDH(3, "192");
                LDH(4, "256"); LDH(5, "320"); LDH(6, "384"); LDH(7, "448");
#undef LDH
                asm volatile("s_waitcnt vmcnt(0)" ::: "memory");
                __builtin_amdgcn_sched_barrier(0);

                // ---- MFMA: K=256, 2 independent chains ----
                f32x4 a0 = (f32x4){0.f, 0.f, 0.f, 0.f};
                f32x4 a1 = (f32x4){0.f, 0.f, 0.f, 0.f};
#pragma unroll
                for (int kk = 0; kk < 8; kk += 2) {
                    a0 = __builtin_amdgcn_mfma_f32_16x16x32_bf16(av[kk],     rB[kk],     a0, 0, 0, 0);
                    a1 = __builtin_amdgcn_mfma_f32_16x16x32_bf16(av[kk + 1], rB[kk + 1], a1, 0, 0, 0);
                }
                partial[G][t & 1][w][ln] = a0 + a1;
                asm volatile("s_waitcnt lgkmcnt(0)" ::: "memory");
                __builtin_amdgcn_sched_barrier(0);
                if (ln == 0) *((volatile int*)&done_sh[G][w]) = t + 1;
            }
        }
    } else if (w < 6) {
        // ================= gate role =================
        int G = w - 4;
        float cs = 0.f, ns = 0.f, ms = 0.f;
        volatile int* dp = &done_sh[G][ln & 3];

        for (int t = 0; t < Tsz; ++t) {
            // ---- wait for all 4 MFMA partials of this step ----
            while (__any(*dp < t + 1)) { }
            __builtin_amdgcn_sched_barrier(0);

            // ---- reduce 4 K-slices, transpose via proj (within-wave) ----
            f32x4 s = partial[G][t & 1][0][ln];
            s += partial[G][t & 1][1][ln];
            s += partial[G][t & 1][2][ln];
            s += partial[G][t & 1][3][ln];
#pragma unroll
            for (int r = 0; r < 4; ++r) proj[G][quad * 4 + r][c15] = s[r];
            asm volatile("s_waitcnt lgkmcnt(0)" ::: "memory");
            __builtin_amdgcn_sched_barrier(0);

            // x_proj prefetch (issued last step) is complete by now
            asm volatile("s_waitcnt vmcnt(0)" : "+v"(xr4), "+v"(xr2) :: "memory");
            __builtin_amdgcn_sched_barrier(0);
            float xv0, xv1, xv2, xv3;
            if (xp32) { xv0 = xr4[0]; xv1 = xr4[1]; xv2 = xr4[2]; xv3 = xr4[3]; }
            else {
                xv0 = bf2f((u16)(xr2[0] & 0xffffu)); xv1 = bf2f((u16)(xr2[0] >> 16));
                xv2 = bf2f((u16)(xr2[1] & 0xffffu)); xv3 = bf2f((u16)(xr2[1] >> 16));
            }

            float ip  = proj[G][bq][du]      + xv0 + bi0;
            float fp_ = proj[G][bq][4 + du]  + xv1 + bi1;
            float op_ = proj[G][bq][8 + du]  + xv2 + bi2;
            float zp  = proj[G][bq][12 + du] + xv3 + bi3;
            float sf = 1.f / (1.f + __expf(-fp_));
            float lf = __logf(sf + 1e-8f);
            float mn = fmaxf(ms + lf, ip);
            float it = __expf(ip - mn);
            float ft = __expf(ms + lf - mn);
            float ot = 1.f / (1.f + __expf(-op_));
            float zt = tanhf(zp);
            cs = ft * cs + it * zt;
            ns = ft * ns + it;
            ms = mn;
            float h = ot * (cs / (ns + 1e-8f));
            out[(size_t)(G * 16 + bq) * (Tsz * Usz) + (size_t)t * Usz + u_g] = h;  // plain (flushed at end)
            u16* hstore = G ? ((t & 1) ? h11 : h10) : ((t & 1) ? h01 : h00);
            u16* hp = hstore + bq * 1024 + u_g;
            unsigned hv = (unsigned)f2bf(h);
            asm volatile("global_store_short %0, %1, off sc0 sc1" :: "v"(hp), "v"(hv) : "memory");
            asm volatile("s_waitcnt vmcnt(0)" ::: "memory");   // h (+out) ack'd in LLC
            __builtin_amdgcn_sched_barrier(0);
            if (ln == 0) {
                unsigned* fm = (G ? flags1 : flags0) + blk;
                unsigned val = (unsigned)(t + 2);
                asm volatile("global_store_dword %0, %1, off sc0 sc1" :: "v"(fm), "v"(val) : "memory");
            }
            // issue x_proj prefetch for t+1; drained before next use
            int tn = (t + 1 < Tsz) ? t + 1 : t;
            size_t o = ((size_t)tn * Bsz + (G * 16 + bq)) * Gsz + blk * 16 + du * 4;
            if (xp32) {
                const float* p = xpf + o;
                asm volatile("global_load_dwordx4 %0, %1, off" : "=v"(xr4) : "v"(p));
            } else {
                const u16* p = xph + o;
                asm volatile("global_load_dwordx2 %0, %1, off" : "=v"(xr2) : "v"(p));
            }
        }
    } else {
        // ================= sentinel role =================
        int G = w - 6;
        const unsigned* fp4 = (G ? flags1 : flags0) + ln * 4;
        for (int s = 1; s <= Tsz; ++s) {
            unsigned tgt = (unsigned)s;
            u32x4 fv;
            do {
                asm volatile("global_load_dwordx4 %0, %1, off sc0 sc1\n\ts_waitcnt vmcnt(0)"
                             : "=v"(fv) : "v"(fp4) : "memory");
            } while (__any((int)(fv[0] < tgt || fv[1] < tgt || fv[2] < tgt || fv[3] < tgt)));
            __builtin_amdgcn_sched_barrier(0);
            if (ln == 0) *((volatile int*)&ready_sh[G]) = s;
        }
    }
}

// =====================================================================
extern "C" void kernel_launch(void* const* d_in, const int* in_sizes, int n_in,
                              void* d_out, int out_size, void* d_ws, size_t ws_size,
                              hipStream_t stream) {
    const float* x    = (const float*)d_in[0];
    const float* W    = (const float*)d_in[1];
    const float* R    = (const float*)d_in[2];
    const float* bias = (const float*)d_in[3];
    float* out = (float*)d_out;

    char* ws = (char*)d_ws;
    size_t off = 0;
    u16* Af = (u16*)(ws + off); off += (size_t)16384 * 1024 * 2;  // 32MB
    u16* Bf = (u16*)(ws + off); off += (size_t)1024 * 4096 * 2;   // 8MB
    u16* Rp = (u16*)(ws + off); off += (size_t)1024 * 4096 * 2;   // 8MB
    u16* hbf = (u16*)(ws + off); off += (size_t)1 << 20;          // 1MB (4x32KB used)
    unsigned* flags = (unsigned*)(ws + off); off += 4096;         // 512 flags used
    size_t xp_need32 = (size_t)16384 * 4096 * 4;                  // 256MB
    int xp32 = (ws_size >= off + xp_need32) ? 1 : 0;
    float* xpf = (float*)(ws + off);
    u16*   xph = (u16*)(ws + off);

    pack_a<<<dim3(8192), dim3(256), 0, stream>>>(x, Af);
    pack_b<<<dim3(2048), dim3(256), 0, stream>>>(W, Bf);
    pack_r<<<dim3(2048), dim3(256), 0, stream>>>(R, Rp, flags);
    gemm1<<<dim3(4096), dim3(256), 0, stream>>>(Af, Bf, xpf, xph, xp32);

    void* args[] = { (void*)&xpf, (void*)&xph, (void*)&xp32, (void*)&Rp,
                     (void*)&bias, (void*)&hbf, (void*)&out, (void*)&flags };
    hipLaunchCooperativeKernel((const void*)scan_all, dim3(256), dim3(512), args, 0, stream);
}

// Round 6
// 3783.669 us; speedup vs baseline: 1.3395x; 1.3395x over previous
//
#include <hip/hip_runtime.h>

typedef unsigned short u16;
typedef short short8 __attribute__((ext_vector_type(8)));
typedef float f32x4 __attribute__((ext_vector_type(4)));
typedef unsigned int u32x4 __attribute__((ext_vector_type(4)));
typedef unsigned int u32x2 __attribute__((ext_vector_type(2)));
typedef unsigned short u16x4 __attribute__((ext_vector_type(4)));

#define Bsz 32
#define Tsz 512
#define Dsz 1024
#define Usz 1024
#define Gsz 4096   // 4*U

// ---- bf16 helpers (manual RNE) ----
static __device__ __forceinline__ u16 f2bf(float f) {
    unsigned int u = __float_as_uint(f);
    unsigned int lsb = (u >> 16) & 1u;
    u += 0x7fffu + lsb;
    return (u16)(u >> 16);
}
static __device__ __forceinline__ float bf2f(u16 b) {
    return __uint_as_float(((unsigned int)b) << 16);
}

// =====================================================================
// Pack kernels: MFMA-fragment-ordered bf16 buffers.
// A-frag (16x16x32): lane L holds A[m = mt*16 + (L&15)][k = kb*32 + (L>>4)*8 + j]
// B-frag:            lane L holds B[k = kb*32 + (L>>4)*8 + j][n = nt*16 + (L&15)]
// Flat: buf[((tile*32 + kb)*64 + L)*8 + j] -> lane-contiguous 16B chunks.
// =====================================================================

__global__ __launch_bounds__(256) void pack_a(const float* __restrict__ x, u16* __restrict__ Af) {
    size_t tid = (size_t)blockIdx.x * 256 + threadIdx.x;
    int L = (int)(tid & 63);
    size_t mtkb = tid >> 6;
    int kb = (int)(mtkb & 31);
    int mt = (int)(mtkb >> 5);
    int m  = mt * 16 + (L & 15);
    int d0 = kb * 32 + (L >> 4) * 8;
    const float* src = x + (size_t)m * Dsz + d0;
    short8 v;
#pragma unroll
    for (int j = 0; j < 8; ++j) v[j] = (short)f2bf(src[j]);
    *(short8*)(Af + tid * 8) = v;
}

__global__ __launch_bounds__(256) void pack_b(const float* __restrict__ W, u16* __restrict__ Bf) {
    size_t tid = (size_t)blockIdx.x * 256 + threadIdx.x;
    int L = (int)(tid & 63);
    size_t ntkb = tid >> 6;
    int kb = (int)(ntkb & 31);
    int nt = (int)(ntkb >> 5);
    int n  = nt * 16 + (L & 15);
    int k0 = kb * 32 + (L >> 4) * 8;
    short8 v;
#pragma unroll
    for (int j = 0; j < 8; ++j) v[j] = (short)f2bf(W[(size_t)(k0 + j) * Gsz + n]);
    *(short8*)(Bf + tid * 8) = v;
}

// R -> Rp gate-interleaved: tile (0..255) covers u = tile*4 + du, col c=gate*4+du
// -> g = gate*1024 + tile*4 + du.  Scan block blk (of 128) stages tiles 2blk,2blk+1.
// Also zeroes the barrier flags (two groups; ws is poisoned 0xAA before every call!).
__global__ __launch_bounds__(256) void pack_r(const float* __restrict__ R, u16* __restrict__ Rp,
                                              unsigned* __restrict__ flags) {
    if (blockIdx.x < 2) flags[blockIdx.x * 256 + threadIdx.x] = 0;
    size_t tid = (size_t)blockIdx.x * 256 + threadIdx.x;
    int L = (int)(tid & 63);
    size_t bkkb = tid >> 6;
    int kb  = (int)(bkkb & 31);
    int blk = (int)(bkkb >> 5);
    int c = L & 15;
    int gate = c >> 2, du = c & 3;
    int g = gate * 1024 + blk * 4 + du;
    int k0 = kb * 32 + (L >> 4) * 8;
    short8 v;
#pragma unroll
    for (int j = 0; j < 8; ++j) v[j] = (short)f2bf(R[(size_t)(k0 + j) * Gsz + g]);
    *(short8*)(Rp + tid * 8) = v;
}

// =====================================================================
// GEMM1: x_proj = X @ W; 128x128 tile, 4 waves. Epilogue writes the
// scan-friendly layout: [t][b][tile(256)][du(4)][gate(4)] so each scan
// gate-lane reads exactly one float4/u16x4 per (t,b,tile).
// =====================================================================
__global__ __launch_bounds__(256) void gemm1(const u16* __restrict__ Af, const u16* __restrict__ Bf,
                                             float* __restrict__ xpf, u16* __restrict__ xph, int xp32) {
    __shared__ u16 smem[16 * 512];
    int bm = blockIdx.x >> 5;
    int bn = blockIdx.x & 31;
    int tid = threadIdx.x;
    int w = tid >> 6, ln = tid & 63;
    int mw = w & 1, nw = w >> 1;

    f32x4 acc[4][4];
#pragma unroll
    for (int i = 0; i < 4; ++i)
#pragma unroll
        for (int j = 0; j < 4; ++j) acc[i][j] = (f32x4){0.f, 0.f, 0.f, 0.f};

    for (int kb = 0; kb < 32; ++kb) {
        short8 tmp[4];
#pragma unroll
        for (int c2 = 0; c2 < 4; ++c2) {
            int chunk = w * 4 + c2;
            const u16* src = (chunk < 8)
                ? Af + (((size_t)(bm * 8 + chunk) * 32 + kb) * 64 + ln) * 8
                : Bf + (((size_t)(bn * 8 + (chunk - 8)) * 32 + kb) * 64 + ln) * 8;
            tmp[c2] = *(const short8*)src;
        }
#pragma unroll
        for (int c2 = 0; c2 < 4; ++c2) {
            int chunk = w * 4 + c2;
            *(short8*)(smem + chunk * 512 + ln * 8) = tmp[c2];
        }
        __syncthreads();
        short8 av[4], bv[4];
#pragma unroll
        for (int i = 0; i < 4; ++i) av[i] = *(const short8*)(smem + (mw * 4 + i) * 512 + ln * 8);
#pragma unroll
        for (int j = 0; j < 4; ++j) bv[j] = *(const short8*)(smem + (8 + nw * 4 + j) * 512 + ln * 8);
#pragma unroll
        for (int i = 0; i < 4; ++i)
#pragma unroll
            for (int j = 0; j < 4; ++j)
                acc[i][j] = __builtin_amdgcn_mfma_f32_16x16x32_bf16(av[i], bv[j], acc[i][j], 0, 0, 0);
        __syncthreads();
    }

    int quad = ln >> 4, c15 = ln & 15;
#pragma unroll
    for (int i = 0; i < 4; ++i) {
        int mt_g = bm * 8 + mw * 4 + i;
#pragma unroll
        for (int j = 0; j < 4; ++j) {
            int g = (bn * 8 + nw * 4 + j) * 16 + c15;
            int p = ((g & 1023) >> 2) * 16 + (g & 3) * 4 + (g >> 10);
#pragma unroll
            for (int r = 0; r < 4; ++r) {
                int row = mt_g * 16 + quad * 4 + r;
                int bb = row >> 9, tt = row & 511;
                size_t o = ((size_t)tt * Bsz + bb) * Gsz + p;
                if (xp32) xpf[o] = acc[i][j][r];
                else      xph[o] = f2bf(acc[i][j][r]);
            }
        }
    }
}

// =====================================================================
// Scan: 128 blocks x 384 threads (6 waves), TWO batch-group chains
// (G0 = batches 0..15, G1 = 16..31).  Each block owns 8 u-dims
// (= Rp tiles 2blk, 2blk+1; 64KB of R in LDS).
//   waves 0-3 : MFMA (K-slice w*256, alternating G0/G1 phases)
//   wave  4/5 : gate wave for G0/G1
// NO __syncthreads in the steady loop.  Handoffs:
//   MFMA  : poll global flags_G >= t+1 (2 flags/lane, own incl.;
//           s_sleep 1 between retries to avoid LLC poll-storm) ->
//           bypass-load h (8 x 16B/lane) -> MFMA (B via ds_read_b128)
//           -> partial[G][t&1][w] -> lgkmcnt(0) -> done[G][w] = t+1
//   gate G: spin done[G][*] >= t+1 (s_sleep between retries) ->
//           reduce -> gates(x2 u-quads) -> bypass-store h -> vmcnt(0)
//           -> flag_G = t+2 -> out stores -> x_proj prefetch (t+1)
// Race freedom: MFMA at (G,t+2) overwrites partial[G][t&1]; it is gated
// by flags >= t+3 everywhere incl. own block => own gate finished t+1
// => partial[G][t&1] consumed.  h parity buffers: gate t+2 overwrites
// parity(t) only after flags >= t+3 => all blocks' MFMA t+1 h-reads
// (drained by their vmcnt(0) before done-post) completed.
// =====================================================================
__global__ __launch_bounds__(384) void scan_all(const float* __restrict__ xpf,
                                                const u16* __restrict__ xph, int xp32,
                                                const u16* __restrict__ Rp,
                                                const float* __restrict__ bias,
                                                u16* __restrict__ hbf, float* __restrict__ out,
                                                unsigned* __restrict__ flags) {
    __shared__ u16 lds_r[32768];                // 64KB: tiles 2blk,2blk+1, fragment order
    __shared__ f32x4 partial[2][2][4][2][64];   // 32KB: [G][par][w][j][ln]
    __shared__ float proj[2][16][2][17];        // 8.5KB: [G][row][j][c]
    __shared__ int done_sh[2][4];               // MFMA -> gate

    int tid = threadIdx.x;
    int blk = blockIdx.x;
    int w = tid >> 6, ln = tid & 63, quad = ln >> 4, c15 = ln & 15;
    int bq = ln >> 2, du = ln & 3;              // gate-wave lane decomposition
    int u0 = blk * 8 + du, u1 = u0 + 4;

    unsigned* flags0 = flags;                   // group 0 flags[128]
    unsigned* flags1 = flags + 128;             // group 1 flags[128]

    u16* h00 = hbf;                             // G0 parity0 (written at even t)
    u16* h01 = hbf + 16384;                     // G0 parity1 (odd t; zeros for t=0)
    u16* h10 = hbf + 32768;                     // G1 parity0
    u16* h11 = hbf + 49152;                     // G1 parity1

    if (tid < 8) ((int*)done_sh)[tid] = 0;

    // ---- stage Rp slice (64KB) into LDS, fragment order preserved ----
    for (int c = tid; c < 4096; c += 384)
        *(short8*)(lds_r + (size_t)c * 8) = *(const short8*)(Rp + (size_t)blk * 32768 + (size_t)c * 8);

    // ---- zero h_{-1} (parity-1 buffers, both groups) via bypass stores ----
    if (tid < 256) {
        u32x4 z = (u32x4){0u, 0u, 0u, 0u};
#pragma unroll
        for (int i = 0; i < 8; ++i) {
            u16* p0 = h01 + tid * 64 + i * 8;
            u16* p1 = h11 + tid * 64 + i * 8;
            asm volatile("global_store_dwordx4 %0, %1, off sc0 sc1" :: "v"(p0), "v"(z) : "memory");
            asm volatile("global_store_dwordx4 %0, %1, off sc0 sc1" :: "v"(p1), "v"(z) : "memory");
        }
    }

    float bi00 = 0.f, bi01 = 0.f, bi02 = 0.f, bi03 = 0.f;
    float bi10 = 0.f, bi11 = 0.f, bi12 = 0.f, bi13 = 0.f;
    f32x4 xrA4 = (f32x4){0.f, 0.f, 0.f, 0.f}, xrB4 = (f32x4){0.f, 0.f, 0.f, 0.f};
    u32x2 xhA2 = (u32x2){0u, 0u}, xhB2 = (u32x2){0u, 0u};

    if (w >= 4) {                               // gate waves: bias + t=0 x_proj
        int G = w - 4;
        bi00 = bias[u0]; bi01 = bias[1024 + u0]; bi02 = bias[2048 + u0]; bi03 = bias[3072 + u0];
        bi10 = bias[u1]; bi11 = bias[1024 + u1]; bi12 = bias[2048 + u1]; bi13 = bias[3072 + u1];
        size_t oA = (size_t)(G * 16 + bq) * Gsz + blk * 32 + du * 4;
        size_t oB = oA + 16;
        if (xp32) { xrA4 = *(const f32x4*)(xpf + oA); xrB4 = *(const f32x4*)(xpf + oB); }
        else      { xhA2 = *(const u32x2*)(xph + oA); xhB2 = *(const u32x2*)(xph + oB); }
    }
    asm volatile("s_waitcnt vmcnt(0)" ::: "memory");
    __builtin_amdgcn_sched_barrier(0);
    __syncthreads();
    if (tid == 0) {
        unsigned one = 1;
        unsigned* f0 = flags0 + blk;
        unsigned* f1 = flags1 + blk;
        asm volatile("global_store_dword %0, %1, off sc0 sc1" :: "v"(f0), "v"(one) : "memory");
        asm volatile("global_store_dword %0, %1, off sc0 sc1" :: "v"(f1), "v"(one) : "memory");
    }

    if (w < 4) {
        // ================= MFMA role =================
        const u16* b00 = h00 + (size_t)c15 * 1024 + w * 256 + quad * 8;
        const u16* b01 = h01 + (size_t)c15 * 1024 + w * 256 + quad * 8;
        const u16* b10 = h10 + (size_t)c15 * 1024 + w * 256 + quad * 8;
        const u16* b11 = h11 + (size_t)c15 * 1024 + w * 256 + quad * 8;

        for (int t = 0; t < Tsz; ++t) {
#pragma unroll
            for (int G = 0; G < 2; ++G) {
                // ---- poll 128 global flags, 2/lane; sleep between retries ----
                const unsigned* fp2 = (G ? flags1 : flags0) + ln * 2;
                unsigned tgt = (unsigned)(t + 1);
                u32x2 fv;
                for (;;) {
                    asm volatile("global_load_dwordx2 %0, %1, off sc0 sc1\n\ts_waitcnt vmcnt(0)"
                                 : "=v"(fv) : "v"(fp2) : "memory");
                    if (!__any((int)(fv[0] < tgt || fv[1] < tgt))) break;
                    asm volatile("s_sleep 1" ::: "memory");
                }
                __builtin_amdgcn_sched_barrier(0);

                // ---- bypass-load this wave's h_{t-1} fragment (8 x 16B/lane) ----
                const u16* aBw = G ? ((t & 1) ? b10 : b11) : ((t & 1) ? b00 : b01);
                short8 av[8];
#define LDH(i, OFF) asm volatile("global_load_dwordx4 %0, %1, off offset:" OFF " sc0 sc1" \
                                 : "=v"(av[i]) : "v"(aBw))
                LDH(0, "0");   LDH(1, "64");  LDH(2, "128"); LDH(3, "192");
                LDH(4, "256"); LDH(5, "320"); LDH(6, "384"); LDH(7, "448");
#undef LDH
                asm volatile("s_waitcnt vmcnt(0)" ::: "memory");
                __builtin_amdgcn_sched_barrier(0);

                // ---- MFMA: K=256, 2 n-tiles, B via ds_read_b128 ----
                f32x4 a0 = (f32x4){0.f, 0.f, 0.f, 0.f};
                f32x4 a1 = (f32x4){0.f, 0.f, 0.f, 0.f};
#pragma unroll
                for (int kk = 0; kk < 8; ++kk) {
                    short8 bt0 = *(const short8*)(lds_r + (size_t)(((0 * 32) + (w * 8 + kk)) * 64 + ln) * 8);
                    short8 bt1 = *(const short8*)(lds_r + (size_t)(((1 * 32) + (w * 8 + kk)) * 64 + ln) * 8);
                    a0 = __builtin_amdgcn_mfma_f32_16x16x32_bf16(av[kk], bt0, a0, 0, 0, 0);
                    a1 = __builtin_amdgcn_mfma_f32_16x16x32_bf16(av[kk], bt1, a1, 0, 0, 0);
                }
                partial[G][t & 1][w][0][ln] = a0;
                partial[G][t & 1][w][1][ln] = a1;
                asm volatile("s_waitcnt lgkmcnt(0)" ::: "memory");
                __builtin_amdgcn_sched_barrier(0);
                if (ln == 0) *((volatile int*)&done_sh[G][w]) = t + 1;
            }
        }
    } else {
        // ================= gate role =================
        int G = w - 4;
        float cs0 = 0.f, ns0 = 0.f, ms0 = 0.f;
        float cs1 = 0.f, ns1 = 0.f, ms1 = 0.f;
        volatile int* dp = &done_sh[G][ln & 3];

        for (int t = 0; t < Tsz; ++t) {
            // ---- wait for all 4 MFMA partials of this step ----
            while (__any(*dp < t + 1)) {
                asm volatile("s_sleep 1" ::: "memory");
            }
            __builtin_amdgcn_sched_barrier(0);

            int par = t & 1;
            f32x4 s0 = partial[G][par][0][0][ln];
            s0 += partial[G][par][1][0][ln];
            s0 += partial[G][par][2][0][ln];
            s0 += partial[G][par][3][0][ln];
            f32x4 s1 = partial[G][par][0][1][ln];
            s1 += partial[G][par][1][1][ln];
            s1 += partial[G][par][2][1][ln];
            s1 += partial[G][par][3][1][ln];
#pragma unroll
            for (int r = 0; r < 4; ++r) {
                proj[G][quad * 4 + r][0][c15] = s0[r];
                proj[G][quad * 4 + r][1][c15] = s1[r];
            }
            asm volatile("s_waitcnt lgkmcnt(0)" ::: "memory");
            __builtin_amdgcn_sched_barrier(0);

            // x_proj prefetch (issued last step) is complete by now
            asm volatile("s_waitcnt vmcnt(0)" : "+v"(xrA4), "+v"(xrB4), "+v"(xhA2), "+v"(xhB2) :: "memory");
            __builtin_amdgcn_sched_barrier(0);

            float h0, h1;
            {   // ---- gates, u-quad 0 ----
                float xv0, xv1, xv2, xv3;
                if (xp32) { xv0 = xrA4[0]; xv1 = xrA4[1]; xv2 = xrA4[2]; xv3 = xrA4[3]; }
                else {
                    xv0 = bf2f((u16)(xhA2[0] & 0xffffu)); xv1 = bf2f((u16)(xhA2[0] >> 16));
                    xv2 = bf2f((u16)(xhA2[1] & 0xffffu)); xv3 = bf2f((u16)(xhA2[1] >> 16));
                }
                float ip  = proj[G][bq][0][du]      + xv0 + bi00;
                float fp_ = proj[G][bq][0][4 + du]  + xv1 + bi01;
                float op_ = proj[G][bq][0][8 + du]  + xv2 + bi02;
                float zp  = proj[G][bq][0][12 + du] + xv3 + bi03;
                float sf = 1.f / (1.f + __expf(-fp_));
                float lf = __logf(sf + 1e-8f);
                float mn = fmaxf(ms0 + lf, ip);
                float it = __expf(ip - mn);
                float ft = __expf(ms0 + lf - mn);
                float ot = 1.f / (1.f + __expf(-op_));
                float zt = tanhf(zp);
                cs0 = ft * cs0 + it * zt;
                ns0 = ft * ns0 + it;
                ms0 = mn;
                h0 = ot * (cs0 / (ns0 + 1e-8f));
            }
            {   // ---- gates, u-quad 1 ----
                float xv0, xv1, xv2, xv3;
                if (xp32) { xv0 = xrB4[0]; xv1 = xrB4[1]; xv2 = xrB4[2]; xv3 = xrB4[3]; }
                else {
                    xv0 = bf2f((u16)(xhB2[0] & 0xffffu)); xv1 = bf2f((u16)(xhB2[0] >> 16));
                    xv2 = bf2f((u16)(xhB2[1] & 0xffffu)); xv3 = bf2f((u16)(xhB2[1] >> 16));
                }
                float ip  = proj[G][bq][1][du]      + xv0 + bi10;
                float fp_ = proj[G][bq][1][4 + du]  + xv1 + bi11;
                float op_ = proj[G][bq][1][8 + du]  + xv2 + bi12;
                float zp  = proj[G][bq][1][12 + du] + xv3 + bi13;
                float sf = 1.f / (1.f + __expf(-fp_));
                float lf = __logf(sf + 1e-8f);
                float mn = fmaxf(ms1 + lf, ip);
                float it = __expf(ip - mn);
                float ft = __expf(ms1 + lf - mn);
                float ot = 1.f / (1.f + __expf(-op_));
                float zt = tanhf(zp);
                cs1 = ft * cs1 + it * zt;
                ns1 = ft * ns1 + it;
                ms1 = mn;
                h1 = ot * (cs1 / (ns1 + 1e-8f));
            }

            // ---- h stores -> ack -> flag; out stores AFTER flag (off the ring) ----
            u16* hstore = G ? ((t & 1) ? h11 : h10) : ((t & 1) ? h01 : h00);
            u16* hp0 = hstore + bq * 1024 + u0;
            u16* hp1 = hstore + bq * 1024 + u1;
            unsigned hv0 = (unsigned)f2bf(h0);
            unsigned hv1 = (unsigned)f2bf(h1);
            asm volatile("global_store_short %0, %1, off sc0 sc1" :: "v"(hp0), "v"(hv0) : "memory");
            asm volatile("global_store_short %0, %1, off sc0 sc1" :: "v"(hp1), "v"(hv1) : "memory");
            asm volatile("s_waitcnt vmcnt(0)" ::: "memory");
            __builtin_amdgcn_sched_barrier(0);
            if (ln == 0) {
                unsigned* fm = (G ? flags1 : flags0) + blk;
                unsigned val = (unsigned)(t + 2);
                asm volatile("global_store_dword %0, %1, off sc0 sc1" :: "v"(fm), "v"(val) : "memory");
            }
            size_t ob = (size_t)(G * 16 + bq) * (Tsz * Usz) + (size_t)t * Usz;
            out[ob + u0] = h0;
            out[ob + u1] = h1;

            // ---- issue x_proj prefetch for t+1 ----
            int tn = (t + 1 < Tsz) ? t + 1 : t;
            size_t oA = ((size_t)tn * Bsz + (G * 16 + bq)) * Gsz + blk * 32 + du * 4;
            if (xp32) {
                const float* pA = xpf + oA;
                const float* pB = xpf + oA + 16;
                asm volatile("global_load_dwordx4 %0, %1, off" : "=v"(xrA4) : "v"(pA));
                asm volatile("global_load_dwordx4 %0, %1, off" : "=v"(xrB4) : "v"(pB));
            } else {
                const u16* pA = xph + oA;
                const u16* pB = xph + oA + 16;
                asm volatile("global_load_dwordx2 %0, %1, off" : "=v"(xhA2) : "v"(pA));
                asm volatile("global_load_dwordx2 %0, %1, off" : "=v"(xhB2) : "v"(pB));
            }
        }
    }
}

// =====================================================================
extern "C" void kernel_launch(void* const* d_in, const int* in_sizes, int n_in,
                              void* d_out, int out_size, void* d_ws, size_t ws_size,
                              hipStream_t stream) {
    const float* x    = (const float*)d_in[0];
    const float* W    = (const float*)d_in[1];
    const float* R    = (const float*)d_in[2];
    const float* bias = (const float*)d_in[3];
    float* out = (float*)d_out;

    char* ws = (char*)d_ws;
    size_t off = 0;
    u16* Af = (u16*)(ws + off); off += (size_t)16384 * 1024 * 2;  // 32MB
    u16* Bf = (u16*)(ws + off); off += (size_t)1024 * 4096 * 2;   // 8MB
    u16* Rp = (u16*)(ws + off); off += (size_t)1024 * 4096 * 2;   // 8MB
    u16* hbf = (u16*)(ws + off); off += (size_t)1 << 20;          // 1MB (4x32KB used)
    unsigned* flags = (unsigned*)(ws + off); off += 4096;         // 256 flags used
    size_t xp_need32 = (size_t)16384 * 4096 * 4;                  // 256MB
    int xp32 = (ws_size >= off + xp_need32) ? 1 : 0;
    float* xpf = (float*)(ws + off);
    u16*   xph = (u16*)(ws + off);

    pack_a<<<dim3(8192), dim3(256), 0, stream>>>(x, Af);
    pack_b<<<dim3(2048), dim3(256), 0, stream>>>(W, Bf);
    pack_r<<<dim3(2048), dim3(256), 0, stream>>>(R, Rp, flags);
    gemm1<<<dim3(4096), dim3(256), 0, stream>>>(Af, Bf, xpf, xph, xp32);

    void* args[] = { (void*)&xpf, (void*)&xph, (void*)&xp32, (void*)&Rp,
                     (void*)&bias, (void*)&hbf, (void*)&out, (void*)&flags };
    hipLaunchCooperativeKernel((const void*)scan_all, dim3(128), dim3(384), args, 0, stream);
}

// Round 7
// 2472.034 us; speedup vs baseline: 2.0502x; 1.5306x over previous
//
#include <hip/hip_runtime.h>

typedef unsigned short u16;
typedef short short8 __attribute__((ext_vector_type(8)));
typedef float f32x4 __attribute__((ext_vector_type(4)));
typedef unsigned int u32x4 __attribute__((ext_vector_type(4)));
typedef unsigned int u32x2 __attribute__((ext_vector_type(2)));

#define Bsz 32
#define Tsz 512
#define Dsz 1024
#define Usz 1024
#define Gsz 4096   // 4*U

#define SENTINEL 0x7FC0u   // bf16 NaN; |h|<1 strictly, so never legit data

// ---- bf16 helpers (manual RNE) ----
static __device__ __forceinline__ u16 f2bf(float f) {
    unsigned int u = __float_as_uint(f);
    unsigned int lsb = (u >> 16) & 1u;
    u += 0x7fffu + lsb;
    return (u16)(u >> 16);
}
static __device__ __forceinline__ float bf2f(u16 b) {
    return __uint_as_float(((unsigned int)b) << 16);
}

// =====================================================================
// Pack kernels: MFMA-fragment-ordered bf16 buffers.
// A-frag (16x16x32): lane L holds A[m = mt*16 + (L&15)][k = kb*32 + (L>>4)*8 + j]
// B-frag:            lane L holds B[k = kb*32 + (L>>4)*8 + j][n = nt*16 + (L&15)]
// Flat: buf[((tile*32 + kb)*64 + L)*8 + j] -> lane-contiguous 16B chunks.
// =====================================================================

__global__ __launch_bounds__(256) void pack_a(const float* __restrict__ x, u16* __restrict__ Af) {
    size_t tid = (size_t)blockIdx.x * 256 + threadIdx.x;
    int L = (int)(tid & 63);
    size_t mtkb = tid >> 6;
    int kb = (int)(mtkb & 31);
    int mt = (int)(mtkb >> 5);
    int m  = mt * 16 + (L & 15);
    int d0 = kb * 32 + (L >> 4) * 8;
    const float* src = x + (size_t)m * Dsz + d0;
    short8 v;
#pragma unroll
    for (int j = 0; j < 8; ++j) v[j] = (short)f2bf(src[j]);
    *(short8*)(Af + tid * 8) = v;
}

__global__ __launch_bounds__(256) void pack_b(const float* __restrict__ W, u16* __restrict__ Bf) {
    size_t tid = (size_t)blockIdx.x * 256 + threadIdx.x;
    int L = (int)(tid & 63);
    size_t ntkb = tid >> 6;
    int kb = (int)(ntkb & 31);
    int nt = (int)(ntkb >> 5);
    int n  = nt * 16 + (L & 15);
    int k0 = kb * 32 + (L >> 4) * 8;
    short8 v;
#pragma unroll
    for (int j = 0; j < 8; ++j) v[j] = (short)f2bf(W[(size_t)(k0 + j) * Gsz + n]);
    *(short8*)(Bf + tid * 8) = v;
}

// R -> Rp gate-interleaved: tile=blk (0..255), col c=gate*4+du -> g=gate*1024+blk*4+du.
// Also initializes the h ring buffers (ws is poisoned 0xAA before every call!):
//   hbf layout: [G(2)][ring p(4)][row(16)][u(1024)] bf16 (each buffer 16384 u16).
//   Ring p=3 holds h_{-1}=0 (read at t=0); p=0,1,2 start as SENTINEL.
__global__ __launch_bounds__(256) void pack_r(const float* __restrict__ R, u16* __restrict__ Rp,
                                              u16* __restrict__ hbf) {
    size_t tid = (size_t)blockIdx.x * 256 + threadIdx.x;
    if (tid < 131072) {
        int p = (int)((tid >> 14) & 3);
        hbf[tid] = (p == 3) ? (u16)0 : (u16)SENTINEL;
    }
    int L = (int)(tid & 63);
    size_t bkkb = tid >> 6;
    int kb  = (int)(bkkb & 31);
    int blk = (int)(bkkb >> 5);
    int c = L & 15;
    int gate = c >> 2, du = c & 3;
    int g = gate * 1024 + blk * 4 + du;
    int k0 = kb * 32 + (L >> 4) * 8;
    short8 v;
#pragma unroll
    for (int j = 0; j < 8; ++j) v[j] = (short)f2bf(R[(size_t)(k0 + j) * Gsz + g]);
    *(short8*)(Rp + tid * 8) = v;
}

// =====================================================================
// GEMM1: x_proj = X @ W; 128x128 tile, 4 waves. Epilogue writes the
// scan-friendly layout: [t][b][tile(256)][du(4)][gate(4)] so each scan
// gate-lane reads exactly one float4/u32x2 per (t,b).
// =====================================================================
__global__ __launch_bounds__(256) void gemm1(const u16* __restrict__ Af, const u16* __restrict__ Bf,
                                             float* __restrict__ xpf, u16* __restrict__ xph, int xp32) {
    __shared__ u16 smem[16 * 512];
    int bm = blockIdx.x >> 5;
    int bn = blockIdx.x & 31;
    int tid = threadIdx.x;
    int w = tid >> 6, ln = tid & 63;
    int mw = w & 1, nw = w >> 1;

    f32x4 acc[4][4];
#pragma unroll
    for (int i = 0; i < 4; ++i)
#pragma unroll
        for (int j = 0; j < 4; ++j) acc[i][j] = (f32x4){0.f, 0.f, 0.f, 0.f};

    for (int kb = 0; kb < 32; ++kb) {
        short8 tmp[4];
#pragma unroll
        for (int c2 = 0; c2 < 4; ++c2) {
            int chunk = w * 4 + c2;
            const u16* src = (chunk < 8)
                ? Af + (((size_t)(bm * 8 + chunk) * 32 + kb) * 64 + ln) * 8
                : Bf + (((size_t)(bn * 8 + (chunk - 8)) * 32 + kb) * 64 + ln) * 8;
            tmp[c2] = *(const short8*)src;
        }
#pragma unroll
        for (int c2 = 0; c2 < 4; ++c2) {
            int chunk = w * 4 + c2;
            *(short8*)(smem + chunk * 512 + ln * 8) = tmp[c2];
        }
        __syncthreads();
        short8 av[4], bv[4];
#pragma unroll
        for (int i = 0; i < 4; ++i) av[i] = *(const short8*)(smem + (mw * 4 + i) * 512 + ln * 8);
#pragma unroll
        for (int j = 0; j < 4; ++j) bv[j] = *(const short8*)(smem + (8 + nw * 4 + j) * 512 + ln * 8);
#pragma unroll
        for (int i = 0; i < 4; ++i)
#pragma unroll
            for (int j = 0; j < 4; ++j)
                acc[i][j] = __builtin_amdgcn_mfma_f32_16x16x32_bf16(av[i], bv[j], acc[i][j], 0, 0, 0);
        __syncthreads();
    }

    int quad = ln >> 4, c15 = ln & 15;
#pragma unroll
    for (int i = 0; i < 4; ++i) {
        int mt_g = bm * 8 + mw * 4 + i;
#pragma unroll
        for (int j = 0; j < 4; ++j) {
            int g = (bn * 8 + nw * 4 + j) * 16 + c15;
            int p = ((g & 1023) >> 2) * 16 + (g & 3) * 4 + (g >> 10);
#pragma unroll
            for (int r = 0; r < 4; ++r) {
                int row = mt_g * 16 + quad * 4 + r;
                int bb = row >> 9, tt = row & 511;
                size_t o = ((size_t)tt * Bsz + bb) * Gsz + p;
                if (xp32) xpf[o] = acc[i][j][r];
                else      xph[o] = f2bf(acc[i][j][r]);
            }
        }
    }
}

// =====================================================================
// Scan: 256 blocks x 384 threads (6 waves) = r3 skeleton (proven best),
// TWO interleaved batch-group chains, ONE barrier per phase, B in LDS.
// NEW (r7): flagless sentinel-validated h broadcast via a 4-deep ring.
//   write @ t -> ring[t&3]; read @ t -> ring[(t+3)&3]; gate tail also
//   re-sentinels its 64 values in ring[(t+2)&3] behind one vmcnt(0).
// MFMA waves load h speculatively (bypass) and validate (bf16 exponent
// all-ones => not yet written => retry with s_sleep).  This removes the
// flag store+ack+poll LLC round trip from the per-phase critical chain.
// Safety: (stale) reader seeing X's h(t+1) implies X's tail-t vmcnt(0)
// (acking both the t-write and the (t+2)-sentinel) committed first;
// (clobber) X writing ring[(t+1)&3] implies X validated all h(t) =>
// every block's MFMA t done => step t-2 reads of that slot complete.
// =====================================================================
__global__ __launch_bounds__(384) void scan_all(const float* __restrict__ xpf,
                                                const u16* __restrict__ xph, int xp32,
                                                const u16* __restrict__ Rp,
                                                const float* __restrict__ bias,
                                                u16* __restrict__ hbf, float* __restrict__ out) {
    __shared__ u16 lds_r[16384];          // 32KB: this block's Rp slice (16 cols x K=1024)
    __shared__ f32x4 partial[2][4][64];   // 8KB: [G][wave][lane]
    __shared__ float proj[2][16][17];     // 2.2KB, per-group

    int tid = threadIdx.x;
    int blk = blockIdx.x;
    int w = tid >> 6, ln = tid & 63, quad = ln >> 4, c15 = ln & 15;
    int bq = ln >> 2, du = ln & 3;        // gate-wave lane decomposition
    int u_g = blk * 4 + du;

    // ---- stage Rp slice into LDS (fragment order preserved) ----
    if (tid < 256) {
#pragma unroll
        for (int i = 0; i < 8; ++i)
            *(short8*)(lds_r + tid * 64 + i * 8) = *(const short8*)(Rp + (size_t)blk * 16384 + tid * 64 + i * 8);
    }

    float bi0 = 0.f, bi1 = 0.f, bi2 = 0.f, bi3 = 0.f;
    float cs = 0.f, ns = 0.f, ms = 0.f;   // gate state (each gate wave serves one G)
    f32x4 xr4 = (f32x4){0.f, 0.f, 0.f, 0.f};
    u32x2 xr2 = (u32x2){0u, 0u};

    if (w >= 4) {                          // gate waves: bias + t=0 x_proj
        int G = w - 4;
        bi0 = bias[u_g]; bi1 = bias[1024 + u_g]; bi2 = bias[2048 + u_g]; bi3 = bias[3072 + u_g];
        size_t o0 = (size_t)(G * 16 + bq) * Gsz + blk * 16 + du * 4;   // t=0
        if (xp32) xr4 = *(const f32x4*)(xpf + o0);
        else      xr2 = *(const u32x2*)(xph + o0);
    }
    __syncthreads();                       // lds_r ready (h ring inited by pack_r)

    auto phase = [&](int G, int t) {
        if (w < 4) {
            // ---- speculative bypass-load + sentinel-validate h_{t-1} ----
            const u16* hbase = hbf + ((size_t)(G * 4 + ((t + 3) & 3)) << 14)
                                   + (size_t)c15 * 1024 + w * 256 + quad * 8;
            short8 av[8];
            for (;;) {
#define LDH(i, OFF) asm volatile("global_load_dwordx4 %0, %1, off offset:" OFF " sc0 sc1" \
                                 : "=v"(av[i]) : "v"(hbase))
                LDH(0, "0");   LDH(1, "64");  LDH(2, "128"); LDH(3, "192");
                LDH(4, "256"); LDH(5, "320"); LDH(6, "384"); LDH(7, "448");
#undef LDH
                asm volatile("s_waitcnt vmcnt(0)" ::: "memory");
                __builtin_amdgcn_sched_barrier(0);
                unsigned bad = 0;
#pragma unroll
                for (int i = 0; i < 8; ++i) {
                    u32x4 xw = __builtin_bit_cast(u32x4, av[i]);
#pragma unroll
                    for (int k = 0; k < 4; ++k) {
                        unsigned m = xw[k] & 0x7F807F80u;
                        bad |= (unsigned)((m >> 16) == 0x7F80u);
                        bad |= (unsigned)((m & 0xFFFFu) == 0x7F80u);
                    }
                }
                if (!__any((int)bad)) break;
                asm volatile("s_sleep 1" ::: "memory");
            }
            __builtin_amdgcn_sched_barrier(0);

            // ---- MFMA: K=256 per wave, 2 independent chains ----
            f32x4 a0 = (f32x4){0.f, 0.f, 0.f, 0.f};
            f32x4 a1 = (f32x4){0.f, 0.f, 0.f, 0.f};
#pragma unroll
            for (int kk = 0; kk < 8; kk += 2) {
                short8 b0 = *(const short8*)(lds_r + ((w * 8 + kk) * 64 + ln) * 8);
                short8 b1 = *(const short8*)(lds_r + ((w * 8 + kk + 1) * 64 + ln) * 8);
                a0 = __builtin_amdgcn_mfma_f32_16x16x32_bf16(av[kk], b0, a0, 0, 0, 0);
                a1 = __builtin_amdgcn_mfma_f32_16x16x32_bf16(av[kk + 1], b1, a1, 0, 0, 0);
            }
            partial[G][w][ln] = a0 + a1;
        }
        __syncthreads();                   // the ONLY barrier this phase
        if (w == 4 + G) {
            // ---- reduce 4 K-slices, transpose via proj (within-wave) ----
            f32x4 s = partial[G][0][ln];
            s += partial[G][1][ln];
            s += partial[G][2][ln];
            s += partial[G][3][ln];
#pragma unroll
            for (int r = 0; r < 4; ++r) proj[G][quad * 4 + r][c15] = s[r];
            asm volatile("s_waitcnt lgkmcnt(0)" ::: "memory");
            __builtin_amdgcn_sched_barrier(0);

            // x_proj prefetch (issued last step for this G) is complete by now
            asm volatile("s_waitcnt vmcnt(0)" : "+v"(xr4), "+v"(xr2) :: "memory");
            __builtin_amdgcn_sched_barrier(0);
            float xv0, xv1, xv2, xv3;
            if (xp32) { xv0 = xr4[0]; xv1 = xr4[1]; xv2 = xr4[2]; xv3 = xr4[3]; }
            else {
                xv0 = bf2f((u16)(xr2[0] & 0xffffu)); xv1 = bf2f((u16)(xr2[0] >> 16));
                xv2 = bf2f((u16)(xr2[1] & 0xffffu)); xv3 = bf2f((u16)(xr2[1] >> 16));
            }

            float ip  = proj[G][bq][du]      + xv0 + bi0;
            float fp_ = proj[G][bq][4 + du]  + xv1 + bi1;
            float op_ = proj[G][bq][8 + du]  + xv2 + bi2;
            float zp  = proj[G][bq][12 + du] + xv3 + bi3;
            float sf = 1.f / (1.f + __expf(-fp_));
            float lf = __logf(sf + 1e-8f);
            float mn = fmaxf(ms + lf, ip);
            float it = __expf(ip - mn);
            float ft = __expf(ms + lf - mn);
            float ot = 1.f / (1.f + __expf(-op_));
            float zt = tanhf(zp);
            cs = ft * cs + it * zt;
            ns = ft * ns + it;
            ms = mn;
            float h = ot * (cs / (ns + 1e-8f));
            out[(size_t)(G * 16 + bq) * (Tsz * Usz) + (size_t)t * Usz + u_g] = h;

            // ---- h store to ring[t&3] + re-sentinel ring[(t+2)&3] ----
            size_t chunk = (size_t)bq * 1024 + u_g;
            u16* hp = hbf + ((size_t)(G * 4 + (t & 3)) << 14) + chunk;
            u16* sp = hbf + ((size_t)(G * 4 + ((t + 2) & 3)) << 14) + chunk;
            unsigned hv = (unsigned)f2bf(h);
            unsigned sv = SENTINEL;
            asm volatile("global_store_short %0, %1, off sc0 sc1" :: "v"(hp), "v"(hv) : "memory");
            asm volatile("global_store_short %0, %1, off sc0 sc1" :: "v"(sp), "v"(sv) : "memory");
            asm volatile("s_waitcnt vmcnt(0)" ::: "memory");   // commit before next step's stores
            __builtin_amdgcn_sched_barrier(0);

            // ---- issue x_proj prefetch for t+1 (left in flight) ----
            int tn = (t + 1 < Tsz) ? t + 1 : t;
            size_t o = ((size_t)tn * Bsz + (G * 16 + bq)) * Gsz + blk * 16 + du * 4;
            if (xp32) {
                const float* p = xpf + o;
                asm volatile("global_load_dwordx4 %0, %1, off" : "=v"(xr4) : "v"(p));
            } else {
                const u16* p = xph + o;
                asm volatile("global_load_dwordx2 %0, %1, off" : "=v"(xr2) : "v"(p));
            }
        }
    };

    for (int t = 0; t < Tsz; ++t) {
        phase(0, t);
        phase(1, t);
    }
}

// =====================================================================
extern "C" void kernel_launch(void* const* d_in, const int* in_sizes, int n_in,
                              void* d_out, int out_size, void* d_ws, size_t ws_size,
                              hipStream_t stream) {
    const float* x    = (const float*)d_in[0];
    const float* W    = (const float*)d_in[1];
    const float* R    = (const float*)d_in[2];
    const float* bias = (const float*)d_in[3];
    float* out = (float*)d_out;

    char* ws = (char*)d_ws;
    size_t off = 0;
    u16* Af = (u16*)(ws + off); off += (size_t)16384 * 1024 * 2;  // 32MB
    u16* Bf = (u16*)(ws + off); off += (size_t)1024 * 4096 * 2;   // 8MB
    u16* Rp = (u16*)(ws + off); off += (size_t)1024 * 4096 * 2;   // 8MB
    u16* hbf = (u16*)(ws + off); off += (size_t)1 << 20;          // 1MB (256KB used: 2G x 4-ring x 32KB)
    off += 4096;                                                  // (old flags slot, unused)
    size_t xp_need32 = (size_t)16384 * 4096 * 4;                  // 256MB
    int xp32 = (ws_size >= off + xp_need32) ? 1 : 0;
    float* xpf = (float*)(ws + off);
    u16*   xph = (u16*)(ws + off);

    pack_a<<<dim3(8192), dim3(256), 0, stream>>>(x, Af);
    pack_b<<<dim3(2048), dim3(256), 0, stream>>>(W, Bf);
    pack_r<<<dim3(2048), dim3(256), 0, stream>>>(R, Rp, hbf);
    gemm1<<<dim3(4096), dim3(256), 0, stream>>>(Af, Bf, xpf, xph, xp32);

    void* args[] = { (void*)&xpf, (void*)&xph, (void*)&xp32, (void*)&Rp,
                     (void*)&bias, (void*)&hbf, (void*)&out };
    hipLaunchCooperativeKernel((const void*)scan_all, dim3(256), dim3(384), args, 0, stream);
}